// Round 11
// baseline (5216.072 us; speedup 1.0000x reference)
//
#include <hip/hip_runtime.h>
#include <hip/hip_bf16.h>

// GestureCNNLSTM: conv1(1->16,3x3,p1)+relu+pool2 -> conv2(16->32,3x3,p1)+relu+pool2
//  -> flatten 192 -> gx GEMM (+b_ih+b_hh) -> 512-step LSTM (H=256) -> 64-dim classifier.
// x [128][512][13][10] f32, out [128][64] f32. feat/gx f16 in ws.
//
// R10: LSTM split 2 blocks/batch-element (256 blocks = 256 CUs). Per block:
// 512 gate rows, weights FULLY resident (56 reg-pairs + 72 LDS-pairs per row,
// 147 KB LDS) -> zero per-step weight streaming (R5-R9 were fill-rate bound on
// 196 KB/step). Per-step 256 B h-exchange via agent-scope release/acquire +
// threadfence (L2 writeback; XCD-coherence-safe). Co-residency: 1 block/CU
// (LDS-forced) x grid 256 = CU count. Flags memset each launch.

typedef _Float16 half2v __attribute__((ext_vector_type(2)));
typedef _Float16 f16x8 __attribute__((ext_vector_type(8)));
typedef float f32x4 __attribute__((ext_vector_type(4)));

__device__ __forceinline__ float dot2f16(half2v a, half2v b, float c) {
#if defined(__has_builtin)
#if __has_builtin(__builtin_amdgcn_fdot2)
    return __builtin_amdgcn_fdot2(a, b, c, false);
#else
    return c + (float)a.x * (float)b.x + (float)a.y * (float)b.y;
#endif
#else
    return c + (float)a.x * (float)b.x + (float)a.y * (float)b.y;
#endif
}

__device__ __forceinline__ float dot2u(unsigned int a, unsigned int b, float c) {
    return dot2f16(__builtin_bit_cast(half2v, a), __builtin_bit_cast(half2v, b), c);
}

__device__ __forceinline__ unsigned int packf2(const float* p) {
    half2v hv;
    hv.x = (_Float16)p[0];
    hv.y = (_Float16)p[1];
    return __builtin_bit_cast(unsigned int, hv);
}

__device__ __forceinline__ unsigned int packff(float a, float b) {
    half2v hv;
    hv.x = (_Float16)a;
    hv.y = (_Float16)b;
    return __builtin_bit_cast(unsigned int, hv);
}

__device__ __forceinline__ half2v bch2(unsigned int u) {
    return __builtin_bit_cast(half2v, u);
}

__device__ __forceinline__ uint4 pack8(const float* p) {
    uint4 v;
    v.x = packf2(p + 0);
    v.y = packf2(p + 2);
    v.z = packf2(p + 4);
    v.w = packf2(p + 6);
    return v;
}

// ---------------- Kernel P1: pre-pack Wih (f32 -> f16), once ----------------
__global__ __launch_bounds__(256) void prepack_w_kernel(
    const float* __restrict__ Wih, uint4* __restrict__ wf)
{
    int idx = blockIdx.x * 256 + threadIdx.x;
    if (idx < 1024 * 192 / 8) wf[idx] = pack8(Wih + idx * 8);
}

// ---------------- Kernel A: fused conv1+pool1+conv2+pool2 ----------------
__global__ __launch_bounds__(256) void conv_kernel(
    const float* __restrict__ x,     // [65536][13][10]
    const float* __restrict__ c1w,   // [16][1][3][3]
    const float* __restrict__ c1b,   // [16]
    const float* __restrict__ c2w,   // [32][16][3][3]
    const float* __restrict__ c2b,   // [32]
    _Float16* __restrict__ feat)     // [65536][192]
{
    __shared__ float w1t[9 * 16];
    __shared__ float b1s[16];
    __shared__ unsigned int w2h[8 * 9 * 32];   // [icp][k][oc]
    __shared__ float b2s[32];
    __shared__ float xp[4][14 * 12];
    __shared__ __align__(4) _Float16 p1ph[4][8 * 7 * 16];  // [y*7+x][oc]

    const int tid = threadIdx.x;

    for (int idx = tid; idx < 144; idx += 256) {
        int oc = idx / 9, k = idx % 9;
        w1t[k * 16 + oc] = c1w[idx];
    }
    if (tid < 16) b1s[tid] = c1b[tid];
    for (int idx = tid; idx < 2304; idx += 256) {
        int icp = idx / 288, rem = idx % 288;
        int k = rem / 32, oc = rem % 32;
        float a = c2w[oc * 144 + (2 * icp) * 9 + k];
        float b = c2w[oc * 144 + (2 * icp + 1) * 9 + k];
        w2h[idx] = packff(a, b);
    }
    if (tid < 32) b2s[tid] = c2b[tid];

    const int w = tid >> 6;
    const int lane = tid & 63;
    const int img = blockIdx.x * 4 + w;

    for (int i = lane; i < 14 * 12; i += 64) xp[w][i] = 0.f;
    for (int i = lane; i < 8 * 7 * 16; i += 64) p1ph[w][i] = (_Float16)0.f;
    __syncthreads();

    const float* xin = x + (size_t)img * 130;
    for (int i = lane; i < 130; i += 64) {
        int r = i / 10, c = i % 10;
        xp[w][(r + 1) * 12 + (c + 1)] = xin[i];
    }
    __syncthreads();

    {
        const int oc = lane & 15, q = lane >> 4;
        #pragma unroll
        for (int i = 0; i < 8; i++) {
            int pos = i * 4 + q;
            if (pos < 30) {
                int ph = pos / 5, pw = pos % 5;
                float cmax = -1e30f;
                #pragma unroll
                for (int pt = 0; pt < 4; pt++) {
                    int Y = 2 * ph + (pt >> 1), X = 2 * pw + (pt & 1);
                    float s = 0.f;
                    #pragma unroll
                    for (int k = 0; k < 9; k++) {
                        int dy = k / 3, dx = k % 3;
                        s += w1t[k * 16 + oc] * xp[w][(Y + dy) * 12 + X + dx];
                    }
                    cmax = fmaxf(cmax, s);
                }
                p1ph[w][((ph + 1) * 7 + (pw + 1)) * 16 + oc] =
                    (_Float16)fmaxf(0.f, cmax + b1s[oc]);
            }
        }
    }
    __syncthreads();

    {
        const int oc = lane & 31, pw2 = lane >> 5;
        float acc[3][4] = {};
        const _Float16* P = &p1ph[w][0];

        #pragma unroll
        for (int icp = 0; icp < 8; icp++) {
            unsigned int hreg[32];
            #pragma unroll
            for (int y = 0; y < 8; y++)
                #pragma unroll
                for (int xx = 0; xx < 4; xx++) {
                    int xcol = 2 * pw2 + xx;
                    hreg[y * 4 + xx] =
                        *(const unsigned int*)&P[(y * 7 + xcol) * 16 + 2 * icp];
                }
            #pragma unroll
            for (int k = 0; k < 9; k++) {
                int dy = k / 3, dx = k % 3;
                unsigned int wv = w2h[(icp * 9 + k) * 32 + oc];
                #pragma unroll
                for (int ph2 = 0; ph2 < 3; ph2++) {
                    #pragma unroll
                    for (int pt = 0; pt < 4; pt++) {
                        int y = 2 * ph2 + (pt >> 1) + dy;
                        int xx2 = (pt & 1) + dx;
                        acc[ph2][pt] = dot2u(wv, hreg[y * 4 + xx2], acc[ph2][pt]);
                    }
                }
            }
        }
        float bias = b2s[oc];
        _Float16* fo = feat + (size_t)img * 192;
        #pragma unroll
        for (int ph2 = 0; ph2 < 3; ph2++) {
            float m = fmaxf(fmaxf(acc[ph2][0], acc[ph2][1]),
                            fmaxf(acc[ph2][2], acc[ph2][3]));
            fo[oc * 6 + ph2 * 2 + pw2] = (_Float16)fmaxf(0.f, m + bias);
        }
    }
}

// ---------------- Kernel B: gx = feat @ W_ih^T + bias via MFMA f16 ----------
__global__ __launch_bounds__(256, 1) void gemm_gx_kernel(
    const _Float16* __restrict__ feat,  // [65536][192]
    const _Float16* __restrict__ wf16,  // [1024][192] (prepacked)
    const float* __restrict__ bih,
    const float* __restrict__ bhh,
    _Float16* __restrict__ gx)          // [65536][1024]
{
    __shared__ uint4 As4[128][25];
    __shared__ uint4 Ws4[128][25];

    const int tid = threadIdx.x;
    const int n0 = blockIdx.x * 128;
    const int m0 = blockIdx.y * 128;

    #pragma unroll
    for (int it = 0; it < 12; it++) {
        int q = tid + it * 256;
        int r = q / 24, c = q % 24;
        As4[r][c] = *(const uint4*)(feat + (size_t)(m0 + r) * 192 + c * 8);
        Ws4[r][c] = *(const uint4*)(wf16 + (size_t)(n0 + r) * 192 + c * 8);
    }
    __syncthreads();

    const int w = tid >> 6;
    const int lane = tid & 63;
    const int lm = lane & 15;
    const int lk = lane >> 4;

    f32x4 acc[2][8] = {};
    #pragma unroll
    for (int ks = 0; ks < 6; ks++) {
        f16x8 wf[2], af[8];
        #pragma unroll
        for (int nf = 0; nf < 2; nf++)
            wf[nf] = __builtin_bit_cast(f16x8, Ws4[w * 32 + nf * 16 + lm][ks * 4 + lk]);
        #pragma unroll
        for (int mf = 0; mf < 8; mf++)
            af[mf] = __builtin_bit_cast(f16x8, As4[mf * 16 + lm][ks * 4 + lk]);
        #pragma unroll
        for (int nf = 0; nf < 2; nf++)
            #pragma unroll
            for (int mf = 0; mf < 8; mf++)
                acc[nf][mf] = __builtin_amdgcn_mfma_f32_16x16x32_f16(
                    wf[nf], af[mf], acc[nf][mf], 0, 0, 0);
    }

    #pragma unroll
    for (int nf = 0; nf < 2; nf++) {
        int nb = n0 + w * 32 + nf * 16 + lk * 4;
        float4 b1 = *(const float4*)&bih[nb];
        float4 b2 = *(const float4*)&bhh[nb];
        float bs0 = b1.x + b2.x, bs1 = b1.y + b2.y;
        float bs2 = b1.z + b2.z, bs3 = b1.w + b2.w;
        #pragma unroll
        for (int mf = 0; mf < 8; mf++) {
            int m = m0 + mf * 16 + lm;
            union { _Float16 h[4]; uint2 u; } pk;
            pk.h[0] = (_Float16)(acc[nf][mf][0] + bs0);
            pk.h[1] = (_Float16)(acc[nf][mf][1] + bs1);
            pk.h[2] = (_Float16)(acc[nf][mf][2] + bs2);
            pk.h[3] = (_Float16)(acc[nf][mf][3] + bs3);
            *(uint2*)&gx[(size_t)m * 1024 + nb] = pk.u;
        }
    }
}

// ---------------- Kernel C: 512-step LSTM, 2 blocks per batch element --------
// Block bid: b = bid>>1, half = bid&1. Thread t (512): g = t>>7, jj = t&127,
// row = g*256 + half*128 + jj. Weights per row: pairs 0..55 regs, 56..127 LDS.
// h exchange per step: own 128 h -> LDS + global hx[b][parity][.]; release
// flag; spin partner flag; copy partner half global -> LDS.
__global__ __launch_bounds__(512, 2) void lstm2_kernel(
    const _Float16* __restrict__ gx, // [128][512][1024]
    const float* __restrict__ Whh,   // [1024][256]
    _Float16* __restrict__ hx,       // [128][2][256] exchange buffer
    unsigned int* __restrict__ syncf,// [128][2] step counters (zeroed per launch)
    const float* __restrict__ clsw,  // [64][256]
    const float* __restrict__ clsb,  // [64]
    float* __restrict__ out)         // [128][64]
{
    __shared__ uint4 wl[18][512];                    // 147 KB: pairs 56..127
    __shared__ __align__(16) _Float16 hbuf[2][256];  // 1 KB
    __shared__ float xg[512];                        // 2 KB

    const int t = threadIdx.x;
    const int bid = blockIdx.x;
    const int b = bid >> 1, half = bid & 1;
    const int jj = t & 127;
    const int row = (t >> 7) * 256 + half * 128 + jj;

    const float* wrow = Whh + (size_t)row * 256;
    half2v wr[56];
    #pragma unroll
    for (int p = 0; p < 56; p++) wr[p] = bch2(packf2(wrow + 2 * p));
    #pragma unroll
    for (int q = 0; q < 18; q++) wl[q][t] = pack8(wrow + 112 + 8 * q);

    if (t < 256) hbuf[0][t] = (_Float16)0.f;
    __syncthreads();

    float cst = 0.f;
    const _Float16* gxb = gx + (size_t)b * 512 * 1024;
    float ga = (float)gxb[row];
    unsigned int* myflag  = &syncf[(b << 1) | half];
    unsigned int* othflag = &syncf[(b << 1) | (half ^ 1)];

    for (int s = 0; s < 512; s++) {
        _Float16 na = gxb[(size_t)((s + 1) & 511) * 1024 + row];

        float acc = ga;
        const uint4* hb4 = (const uint4*)&hbuf[s & 1][0];  // 32 uint4 chunks
        // REG section: pairs 0..55 <-> h chunks 0..13
        #pragma unroll
        for (int cc = 0; cc < 14; cc++) {
            uint4 hv = hb4[cc];
            acc = dot2f16(wr[4 * cc + 0], bch2(hv.x), acc);
            acc = dot2f16(wr[4 * cc + 1], bch2(hv.y), acc);
            acc = dot2f16(wr[4 * cc + 2], bch2(hv.z), acc);
            acc = dot2f16(wr[4 * cc + 3], bch2(hv.w), acc);
        }
        // LDS section: pairs 56..127 <-> h chunks 14..31
        #pragma unroll
        for (int q = 0; q < 18; q++) {
            uint4 u = wl[q][t];
            uint4 hv = hb4[14 + q];
            acc = dot2f16(bch2(u.x), bch2(hv.x), acc);
            acc = dot2f16(bch2(u.y), bch2(hv.y), acc);
            acc = dot2f16(bch2(u.z), bch2(hv.z), acc);
            acc = dot2f16(bch2(u.w), bch2(hv.w), acc);
        }
        xg[t] = acc;
        __syncthreads();

        if (t < 128) {
            float i_ = 1.f / (1.f + __expf(-xg[t]));
            float f_ = 1.f / (1.f + __expf(-xg[128 + t]));
            float g_ = 1.f - 2.f / (__expf(2.f * xg[256 + t]) + 1.f);
            float o_ = 1.f / (1.f + __expf(-xg[384 + t]));
            cst = f_ * cst + i_ * g_;
            float th = 1.f - 2.f / (__expf(2.f * cst) + 1.f);
            _Float16 h = (_Float16)(o_ * th);
            int j = half * 128 + t;
            hbuf[(s + 1) & 1][j] = h;
            hx[(size_t)((b << 1) | ((s + 1) & 1)) * 256 + j] = h;
        }
        __syncthreads();   // barrier drains vmcnt: h stores in L2
        if (t == 0) {
            __threadfence();   // agent fence: make h visible device-wide
            __hip_atomic_store(myflag, (unsigned)(s + 1),
                               __ATOMIC_RELEASE, __HIP_MEMORY_SCOPE_AGENT);
            while (__hip_atomic_load(othflag, __ATOMIC_RELAXED,
                                     __HIP_MEMORY_SCOPE_AGENT) < (unsigned)(s + 1))
                __builtin_amdgcn_s_sleep(1);
            (void)__hip_atomic_load(othflag, __ATOMIC_ACQUIRE,
                                    __HIP_MEMORY_SCOPE_AGENT);
        }
        __syncthreads();   // acquire (L1/L2 inv) visible to whole CU
        if (t < 32) {
            int pos = (half ^ 1) * 128 + t * 4;
            uint2 v = *(const uint2*)&hx[(size_t)((b << 1) | ((s + 1) & 1)) * 256 + pos];
            *(uint2*)&hbuf[(s + 1) & 1][pos] = v;
        }
        ga = (float)na;
        __syncthreads();   // hbuf[(s+1)&1] complete for next step
    }

    if (half == 0 && t < 64) {
        const float* cw = clsw + t * 256;
        float s2 = clsb[t];
        for (int k = 0; k < 256; k++) s2 += cw[k] * (float)hbuf[0][k];
        out[b * 64 + t] = s2;
    }
}

extern "C" void kernel_launch(void* const* d_in, const int* in_sizes, int n_in,
                              void* d_out, int out_size, void* d_ws, size_t ws_size,
                              hipStream_t stream) {
    const float* x    = (const float*)d_in[0];
    const float* c1w  = (const float*)d_in[1];
    const float* c1b  = (const float*)d_in[2];
    const float* c2w  = (const float*)d_in[3];
    const float* c2b  = (const float*)d_in[4];
    const float* Wih  = (const float*)d_in[5];
    const float* bih  = (const float*)d_in[6];
    const float* Whh  = (const float*)d_in[7];
    const float* bhh  = (const float*)d_in[8];
    const float* clsw = (const float*)d_in[9];
    const float* clsb = (const float*)d_in[10];

    _Float16* feat = (_Float16*)d_ws;                     // 25.2 MB
    _Float16* gx   = feat + (size_t)65536 * 192;          // 134.2 MB
    uint4* aux     = (uint4*)(gx + (size_t)65536 * 1024); // 384 KB (wf16)
    _Float16* hx   = (_Float16*)(aux + 24576);            // 131 KB exchange
    unsigned int* syncf = (unsigned int*)(hx + 128 * 2 * 256); // 1 KB flags
    float* outp = (float*)d_out;

    hipMemsetAsync(syncf, 0, 128 * 2 * sizeof(unsigned int), stream);
    hipLaunchKernelGGL(prepack_w_kernel, dim3(96), dim3(256), 0, stream, Wih, aux);
    hipLaunchKernelGGL(conv_kernel, dim3(16384), dim3(256), 0, stream,
                       x, c1w, c1b, c2w, c2b, feat);
    hipLaunchKernelGGL(gemm_gx_kernel, dim3(8, 512), dim3(256), 0, stream,
                       feat, (const _Float16*)aux, bih, bhh, gx);
    hipLaunchKernelGGL(lstm2_kernel, dim3(256), dim3(512), 0, stream,
                       gx, Whh, hx, syncf, clsw, clsb, outp);
}

// Round 12
// 1104.801 us; speedup vs baseline: 4.7213x; 4.7213x over previous
//
#include <hip/hip_runtime.h>
#include <hip/hip_bf16.h>

// GestureCNNLSTM: conv1(1->16,3x3,p1)+relu+pool2 -> conv2(16->32,3x3,p1)+relu+pool2
//  -> flatten 192 -> gx GEMM (+b_ih+b_hh) -> 512-step LSTM (H=256) -> 64-dim classifier.
// x [128][512][13][10] f32, out [128][64] f32. feat/gx f16 in ws (~159.8 MB).
//
// R11: LSTM reverted to R9 (proven 858us; R10's 2-block split paid ~8us/step in
// cross-XCD handshake). LSTM floor analysis: 512 KB weights > ~330 KB on-CU
// residency -> 196 KB/step cold L2 stream at ~64 B/cyc = the measured 4 K cyc/step.
// GEMM: K-split staging (96 at a time) -> 53 KB LDS -> 2 blocks/CU.

typedef _Float16 half2v __attribute__((ext_vector_type(2)));
typedef _Float16 f16x8 __attribute__((ext_vector_type(8)));
typedef float f32x4 __attribute__((ext_vector_type(4)));

__device__ __forceinline__ float dot2f16(half2v a, half2v b, float c) {
#if defined(__has_builtin)
#if __has_builtin(__builtin_amdgcn_fdot2)
    return __builtin_amdgcn_fdot2(a, b, c, false);
#else
    return c + (float)a.x * (float)b.x + (float)a.y * (float)b.y;
#endif
#else
    return c + (float)a.x * (float)b.x + (float)a.y * (float)b.y;
#endif
}

__device__ __forceinline__ float dot2u(unsigned int a, unsigned int b, float c) {
    return dot2f16(__builtin_bit_cast(half2v, a), __builtin_bit_cast(half2v, b), c);
}

__device__ __forceinline__ unsigned int packf2(const float* p) {
    half2v hv;
    hv.x = (_Float16)p[0];
    hv.y = (_Float16)p[1];
    return __builtin_bit_cast(unsigned int, hv);
}

__device__ __forceinline__ unsigned int packff(float a, float b) {
    half2v hv;
    hv.x = (_Float16)a;
    hv.y = (_Float16)b;
    return __builtin_bit_cast(unsigned int, hv);
}

__device__ __forceinline__ half2v bch2(unsigned int u) {
    return __builtin_bit_cast(half2v, u);
}

__device__ __forceinline__ uint4 pack8(const float* p) {
    uint4 v;
    v.x = packf2(p + 0);
    v.y = packf2(p + 2);
    v.z = packf2(p + 4);
    v.w = packf2(p + 6);
    return v;
}

// ---------------- Kernel P1: pre-pack Wih (f32 -> f16), once ----------------
__global__ __launch_bounds__(256) void prepack_w_kernel(
    const float* __restrict__ Wih, uint4* __restrict__ wf)
{
    int idx = blockIdx.x * 256 + threadIdx.x;
    if (idx < 1024 * 192 / 8) wf[idx] = pack8(Wih + idx * 8);
}

// ---------------- Kernel P2: pre-pack W_hh stream section ----------------
// sw[c][r] (c=0..11, r=0..1023) = pairs 80+4c..80+4c+3 of row r (f32 elems 160+8c..)
__global__ __launch_bounds__(256) void prepack_sw_kernel(
    const float* __restrict__ Whh, uint4* __restrict__ sw)
{
    int idx = blockIdx.x * 256 + threadIdx.x;
    if (idx < 12 * 1024) {
        int c = idx >> 10, r = idx & 1023;
        sw[idx] = pack8(Whh + (size_t)r * 256 + 160 + 8 * c);
    }
}

// ---------------- Kernel A: fused conv1+pool1+conv2+pool2 ----------------
__global__ __launch_bounds__(256) void conv_kernel(
    const float* __restrict__ x,     // [65536][13][10]
    const float* __restrict__ c1w,   // [16][1][3][3]
    const float* __restrict__ c1b,   // [16]
    const float* __restrict__ c2w,   // [32][16][3][3]
    const float* __restrict__ c2b,   // [32]
    _Float16* __restrict__ feat)     // [65536][192]
{
    __shared__ float w1t[9 * 16];
    __shared__ float b1s[16];
    __shared__ unsigned int w2h[8 * 9 * 32];   // [icp][k][oc]
    __shared__ float b2s[32];
    __shared__ float xp[4][14 * 12];
    __shared__ __align__(4) _Float16 p1ph[4][8 * 7 * 16];  // [y*7+x][oc]

    const int tid = threadIdx.x;

    for (int idx = tid; idx < 144; idx += 256) {
        int oc = idx / 9, k = idx % 9;
        w1t[k * 16 + oc] = c1w[idx];
    }
    if (tid < 16) b1s[tid] = c1b[tid];
    for (int idx = tid; idx < 2304; idx += 256) {
        int icp = idx / 288, rem = idx % 288;
        int k = rem / 32, oc = rem % 32;
        float a = c2w[oc * 144 + (2 * icp) * 9 + k];
        float b = c2w[oc * 144 + (2 * icp + 1) * 9 + k];
        w2h[idx] = packff(a, b);
    }
    if (tid < 32) b2s[tid] = c2b[tid];

    const int w = tid >> 6;
    const int lane = tid & 63;
    const int img = blockIdx.x * 4 + w;

    for (int i = lane; i < 14 * 12; i += 64) xp[w][i] = 0.f;
    for (int i = lane; i < 8 * 7 * 16; i += 64) p1ph[w][i] = (_Float16)0.f;
    __syncthreads();

    const float* xin = x + (size_t)img * 130;
    for (int i = lane; i < 130; i += 64) {
        int r = i / 10, c = i % 10;
        xp[w][(r + 1) * 12 + (c + 1)] = xin[i];
    }
    __syncthreads();

    {
        const int oc = lane & 15, q = lane >> 4;
        #pragma unroll
        for (int i = 0; i < 8; i++) {
            int pos = i * 4 + q;
            if (pos < 30) {
                int ph = pos / 5, pw = pos % 5;
                float cmax = -1e30f;
                #pragma unroll
                for (int pt = 0; pt < 4; pt++) {
                    int Y = 2 * ph + (pt >> 1), X = 2 * pw + (pt & 1);
                    float s = 0.f;
                    #pragma unroll
                    for (int k = 0; k < 9; k++) {
                        int dy = k / 3, dx = k % 3;
                        s += w1t[k * 16 + oc] * xp[w][(Y + dy) * 12 + X + dx];
                    }
                    cmax = fmaxf(cmax, s);
                }
                p1ph[w][((ph + 1) * 7 + (pw + 1)) * 16 + oc] =
                    (_Float16)fmaxf(0.f, cmax + b1s[oc]);
            }
        }
    }
    __syncthreads();

    {
        const int oc = lane & 31, pw2 = lane >> 5;
        float acc[3][4] = {};
        const _Float16* P = &p1ph[w][0];

        #pragma unroll
        for (int icp = 0; icp < 8; icp++) {
            unsigned int hreg[32];
            #pragma unroll
            for (int y = 0; y < 8; y++)
                #pragma unroll
                for (int xx = 0; xx < 4; xx++) {
                    int xcol = 2 * pw2 + xx;
                    hreg[y * 4 + xx] =
                        *(const unsigned int*)&P[(y * 7 + xcol) * 16 + 2 * icp];
                }
            #pragma unroll
            for (int k = 0; k < 9; k++) {
                int dy = k / 3, dx = k % 3;
                unsigned int wv = w2h[(icp * 9 + k) * 32 + oc];
                #pragma unroll
                for (int ph2 = 0; ph2 < 3; ph2++) {
                    #pragma unroll
                    for (int pt = 0; pt < 4; pt++) {
                        int y = 2 * ph2 + (pt >> 1) + dy;
                        int xx2 = (pt & 1) + dx;
                        acc[ph2][pt] = dot2u(wv, hreg[y * 4 + xx2], acc[ph2][pt]);
                    }
                }
            }
        }
        float bias = b2s[oc];
        _Float16* fo = feat + (size_t)img * 192;
        #pragma unroll
        for (int ph2 = 0; ph2 < 3; ph2++) {
            float m = fmaxf(fmaxf(acc[ph2][0], acc[ph2][1]),
                            fmaxf(acc[ph2][2], acc[ph2][3]));
            fo[oc * 6 + ph2 * 2 + pw2] = (_Float16)fmaxf(0.f, m + bias);
        }
    }
}

// ---------------- Kernel B: gx = feat @ W_ih^T + bias via MFMA f16 ----------
// 128m x 128n tiles; K staged in TWO halves of 96 -> 53 KB LDS -> 2 blocks/CU.
__global__ __launch_bounds__(256) void gemm_gx_kernel(
    const _Float16* __restrict__ feat,  // [65536][192]
    const _Float16* __restrict__ wf16,  // [1024][192] (prepacked)
    const float* __restrict__ bih,
    const float* __restrict__ bhh,
    _Float16* __restrict__ gx)          // [65536][1024]
{
    __shared__ uint4 As4[128][13];   // 26.6 KB (12 uint4 = K96 + 1 pad)
    __shared__ uint4 Ws4[128][13];   // 26.6 KB

    const int tid = threadIdx.x;
    const int n0 = blockIdx.x * 128;
    const int m0 = blockIdx.y * 128;

    const int w = tid >> 6;
    const int lane = tid & 63;
    const int lm = lane & 15;
    const int lk = lane >> 4;

    f32x4 acc[2][8] = {};

    #pragma unroll
    for (int half = 0; half < 2; half++) {
        if (half) __syncthreads();   // protect LDS reuse
        const int kbase = half * 12; // in uint4 units (96 f16)
        #pragma unroll
        for (int it = 0; it < 6; it++) {
            int q = tid + it * 256;          // 0..1535
            int r = q / 12, c = q % 12;
            As4[r][c] = *(const uint4*)(feat + (size_t)(m0 + r) * 192 + (kbase + c) * 8);
            Ws4[r][c] = *(const uint4*)(wf16 + (size_t)(n0 + r) * 192 + (kbase + c) * 8);
        }
        __syncthreads();

        #pragma unroll
        for (int ks = 0; ks < 3; ks++) {
            f16x8 wf[2], af[8];
            #pragma unroll
            for (int nf = 0; nf < 2; nf++)
                wf[nf] = __builtin_bit_cast(f16x8, Ws4[w * 32 + nf * 16 + lm][ks * 4 + lk]);
            #pragma unroll
            for (int mf = 0; mf < 8; mf++)
                af[mf] = __builtin_bit_cast(f16x8, As4[mf * 16 + lm][ks * 4 + lk]);
            #pragma unroll
            for (int nf = 0; nf < 2; nf++)
                #pragma unroll
                for (int mf = 0; mf < 8; mf++)
                    acc[nf][mf] = __builtin_amdgcn_mfma_f32_16x16x32_f16(
                        wf[nf], af[mf], acc[nf][mf], 0, 0, 0);
        }
    }

    #pragma unroll
    for (int nf = 0; nf < 2; nf++) {
        int nb = n0 + w * 32 + nf * 16 + lk * 4;
        float4 b1 = *(const float4*)&bih[nb];
        float4 b2 = *(const float4*)&bhh[nb];
        float bs0 = b1.x + b2.x, bs1 = b1.y + b2.y;
        float bs2 = b1.z + b2.z, bs3 = b1.w + b2.w;
        #pragma unroll
        for (int mf = 0; mf < 8; mf++) {
            int m = m0 + mf * 16 + lm;
            union { _Float16 h[4]; uint2 u; } pk;
            pk.h[0] = (_Float16)(acc[nf][mf][0] + bs0);
            pk.h[1] = (_Float16)(acc[nf][mf][1] + bs1);
            pk.h[2] = (_Float16)(acc[nf][mf][2] + bs2);
            pk.h[3] = (_Float16)(acc[nf][mf][3] + bs3);
            *(uint2*)&gx[(size_t)m * 1024 + nb] = pk.u;
        }
    }
}

// ---------------- Kernel C: 512-step LSTM + classifier (R9, proven) ----------
// 128 blocks x 512 threads (8 waves, 2/SIMD). Thread t owns rows r0=t, r1=t+512.
// Per row (128 f16 pairs): 0..35 wl4 LDS | 36..37 wl2 LDS | 38..79 regs (42) |
// 80..127 streamed from sw (12 uint4 chunks, L2-hot, zero-reuse cold fetch).
__global__ __launch_bounds__(512, 2) void lstm_kernel(
    const _Float16* __restrict__ gx, // [128][512][1024]
    const float* __restrict__ Whh,   // [1024][256]
    const uint4* __restrict__ sw,    // [12][1024]
    const float* __restrict__ clsw,  // [64][256]
    const float* __restrict__ clsb,  // [64]
    float* __restrict__ out)         // [128][64]
{
    __shared__ uint4 wl4[9][1024];                     // 144 KB: pairs 0..35
    __shared__ uint2 wl2[1024];                        // 8 KB: pairs 36..37
    __shared__ __align__(16) _Float16 hbuf[2][256];    // 1 KB
    __shared__ float xg[512];                          // 2 KB

    const int t = threadIdx.x;
    const int b = blockIdx.x;
    const int r0 = t, r1 = t + 512;

    const float* w0 = Whh + (size_t)r0 * 256;
    const float* w1 = Whh + (size_t)r1 * 256;

    #pragma unroll
    for (int ch = 0; ch < 9; ch++) {
        wl4[ch][r0] = pack8(w0 + 8 * ch);
        wl4[ch][r1] = pack8(w1 + 8 * ch);
    }
    {
        uint2 v0, v1;
        v0.x = packf2(w0 + 72); v0.y = packf2(w0 + 74);
        v1.x = packf2(w1 + 72); v1.y = packf2(w1 + 74);
        wl2[r0] = v0;
        wl2[r1] = v1;
    }
    half2v wr0[42], wr1[42];
    #pragma unroll
    for (int q = 0; q < 42; q++) {
        wr0[q] = bch2(packf2(w0 + 76 + 2 * q));
        wr1[q] = bch2(packf2(w1 + 76 + 2 * q));
    }
    if (t < 256) hbuf[0][t] = (_Float16)0.f;
    __syncthreads();

    float c = 0.f;
    int cur = 0;
    const _Float16* gxb = gx + (size_t)b * 512 * 1024;
    float ga = (float)gxb[r0];
    float gb = (float)gxb[r1];

    for (int step = 0; step < 512; step++) {
        const _Float16* gxn = gxb + (size_t)((step + 1) & 511) * 1024;
        _Float16 na = gxn[r0];
        _Float16 nb = gxn[r1];

        float acc0 = ga, acc1 = gb;
        const uint4* hb4 = (const uint4*)&hbuf[cur][0];  // 32 chunks of 4 pairs

        // STREAM section: h chunks 20..31 <-> sw chunks 0..11
        #pragma unroll
        for (int sc = 0; sc < 12; sc++) {
            uint4 u0 = sw[sc * 1024 + r0];
            uint4 u1 = sw[sc * 1024 + r1];
            uint4 hv = hb4[20 + sc];
            acc0 = dot2f16(bch2(u0.x), bch2(hv.x), acc0);
            acc0 = dot2f16(bch2(u0.y), bch2(hv.y), acc0);
            acc0 = dot2f16(bch2(u0.z), bch2(hv.z), acc0);
            acc0 = dot2f16(bch2(u0.w), bch2(hv.w), acc0);
            acc1 = dot2f16(bch2(u1.x), bch2(hv.x), acc1);
            acc1 = dot2f16(bch2(u1.y), bch2(hv.y), acc1);
            acc1 = dot2f16(bch2(u1.z), bch2(hv.z), acc1);
            acc1 = dot2f16(bch2(u1.w), bch2(hv.w), acc1);
        }
        // LDS wl4: h chunks 0..8
        #pragma unroll
        for (int ch = 0; ch < 9; ch++) {
            uint4 u0 = wl4[ch][r0];
            uint4 u1 = wl4[ch][r1];
            uint4 hv = hb4[ch];
            acc0 = dot2f16(bch2(u0.x), bch2(hv.x), acc0);
            acc0 = dot2f16(bch2(u0.y), bch2(hv.y), acc0);
            acc0 = dot2f16(bch2(u0.z), bch2(hv.z), acc0);
            acc0 = dot2f16(bch2(u0.w), bch2(hv.w), acc0);
            acc1 = dot2f16(bch2(u1.x), bch2(hv.x), acc1);
            acc1 = dot2f16(bch2(u1.y), bch2(hv.y), acc1);
            acc1 = dot2f16(bch2(u1.z), bch2(hv.z), acc1);
            acc1 = dot2f16(bch2(u1.w), bch2(hv.w), acc1);
        }
        // LDS wl2 (pairs 36,37) + regs (pairs 38,39) use h chunk 9
        {
            uint4 hv = hb4[9];
            uint2 u0 = wl2[r0];
            uint2 u1 = wl2[r1];
            acc0 = dot2f16(bch2(u0.x), bch2(hv.x), acc0);
            acc0 = dot2f16(bch2(u0.y), bch2(hv.y), acc0);
            acc1 = dot2f16(bch2(u1.x), bch2(hv.x), acc1);
            acc1 = dot2f16(bch2(u1.y), bch2(hv.y), acc1);
            acc0 = dot2f16(wr0[0], bch2(hv.z), acc0);
            acc0 = dot2f16(wr0[1], bch2(hv.w), acc0);
            acc1 = dot2f16(wr1[0], bch2(hv.z), acc1);
            acc1 = dot2f16(wr1[1], bch2(hv.w), acc1);
        }
        // REG section: h chunks 10..19, wr 2..41
        #pragma unroll
        for (int cc = 0; cc < 10; cc++) {
            uint4 hv = hb4[10 + cc];
            acc0 = dot2f16(wr0[2 + 4 * cc + 0], bch2(hv.x), acc0);
            acc0 = dot2f16(wr0[2 + 4 * cc + 1], bch2(hv.y), acc0);
            acc0 = dot2f16(wr0[2 + 4 * cc + 2], bch2(hv.z), acc0);
            acc0 = dot2f16(wr0[2 + 4 * cc + 3], bch2(hv.w), acc0);
            acc1 = dot2f16(wr1[2 + 4 * cc + 0], bch2(hv.x), acc1);
            acc1 = dot2f16(wr1[2 + 4 * cc + 1], bch2(hv.y), acc1);
            acc1 = dot2f16(wr1[2 + 4 * cc + 2], bch2(hv.z), acc1);
            acc1 = dot2f16(wr1[2 + 4 * cc + 3], bch2(hv.w), acc1);
        }

        if (t >= 256) {           // acc0 = f_j, acc1 = o_j for j = t-256
            xg[t - 256] = acc0;
            xg[t] = acc1;
        }
        __syncthreads();
        if (t < 256) {            // acc0 = i_j, acc1 = g_j for j = t
            float i_ = 1.f / (1.f + __expf(-acc0));
            float g_ = 1.f - 2.f / (__expf(2.f * acc1) + 1.f);
            float f_ = 1.f / (1.f + __expf(-xg[t]));
            float o_ = 1.f / (1.f + __expf(-xg[t + 256]));
            c = f_ * c + i_ * g_;
            float th = 1.f - 2.f / (__expf(2.f * c) + 1.f);
            float h = o_ * th;
            hbuf[cur ^ 1][t] = (_Float16)h;
        }
        __syncthreads();
        cur ^= 1;
        ga = (float)na;
        gb = (float)nb;
    }

    if (t < 64) {
        const float* cw = clsw + t * 256;
        float s = clsb[t];
        for (int k = 0; k < 256; k++) s += cw[k] * (float)hbuf[cur][k];
        out[b * 64 + t] = s;
    }
}

extern "C" void kernel_launch(void* const* d_in, const int* in_sizes, int n_in,
                              void* d_out, int out_size, void* d_ws, size_t ws_size,
                              hipStream_t stream) {
    const float* x    = (const float*)d_in[0];
    const float* c1w  = (const float*)d_in[1];
    const float* c1b  = (const float*)d_in[2];
    const float* c2w  = (const float*)d_in[3];
    const float* c2b  = (const float*)d_in[4];
    const float* Wih  = (const float*)d_in[5];
    const float* bih  = (const float*)d_in[6];
    const float* Whh  = (const float*)d_in[7];
    const float* bhh  = (const float*)d_in[8];
    const float* clsw = (const float*)d_in[9];
    const float* clsb = (const float*)d_in[10];

    _Float16* feat = (_Float16*)d_ws;                     // 25.2 MB
    _Float16* gx   = feat + (size_t)65536 * 192;          // 134.2 MB
    uint4* aux     = (uint4*)(gx + (size_t)65536 * 1024); // 384 KB union:
    // aux = wf16 for gemm, then overwritten as sw for lstm (sequential stream).
    float* outp = (float*)d_out;

    hipLaunchKernelGGL(prepack_w_kernel, dim3(96), dim3(256), 0, stream, Wih, aux);
    hipLaunchKernelGGL(conv_kernel, dim3(16384), dim3(256), 0, stream,
                       x, c1w, c1b, c2w, c2b, feat);
    hipLaunchKernelGGL(gemm_gx_kernel, dim3(8, 512), dim3(256), 0, stream,
                       feat, (const _Float16*)aux, bih, bhh, gx);
    hipLaunchKernelGGL(prepack_sw_kernel, dim3(48), dim3(256), 0, stream, Whh, aux);
    hipLaunchKernelGGL(lstm_kernel, dim3(128), dim3(512), 0, stream,
                       gx, Whh, aux, clsw, clsb, outp);
}